// Round 10
// baseline (904.754 us; speedup 1.0000x reference)
//
#include <hip/hip_runtime.h>
#include <float.h>

// VectorQuantizer: N=262144 rows of D=64 fp32, K=1024 codebook rows.
// out = [x_quantized (N*D f32) | embed_inds (N, written as f32)]
//
// Bit-exact np-fp32 semantics (verified R4): score = fmaf(-2, seq-dot,
// fadd(xnorm, enorm)); pairwise-8 norms; strict < ascending k (first-min).
//
// R10 = R9 (fully scalar SSA, no per-thread arrays) + amdgpu_waves_per_eu(3,3).
// R9 evidence: VGPR=48 (< the 64-float x-row) with zero scratch -> compiler
// REMATERIALIZED x loads inside the k-loop to chase its default high-occupancy
// target (~8 waves/EU -> 64-reg budget) -> 16 extra VMEM loads/k = L1-bound.
// Pinning waves/EU to 3 sets the budget to ~170 and removes the remat
// incentive; 3 waves/SIMD still saturates dep-chain FMA issue (needs 2).

static constexpr int D_DIM = 64;
static constexpr int K_CB  = 1024;
static constexpr int TPB   = 256;      // 1 thread = 1 row; 256 rows/block

// numpy pairwise-8 sum of squares of 64 values held as 16 float4s.
#define NP_INIT(c0, c1)                                                     \
    float ax = __fmul_rn(c0.x, c0.x), ay = __fmul_rn(c0.y, c0.y),           \
          az = __fmul_rn(c0.z, c0.z), aw = __fmul_rn(c0.w, c0.w);           \
    float bx = __fmul_rn(c1.x, c1.x), by = __fmul_rn(c1.y, c1.y),           \
          bz = __fmul_rn(c1.z, c1.z), bw = __fmul_rn(c1.w, c1.w);
#define NP_ACC(ce, co)                                                      \
    ax = __fadd_rn(ax, __fmul_rn(ce.x, ce.x));                              \
    ay = __fadd_rn(ay, __fmul_rn(ce.y, ce.y));                              \
    az = __fadd_rn(az, __fmul_rn(ce.z, ce.z));                              \
    aw = __fadd_rn(aw, __fmul_rn(ce.w, ce.w));                              \
    bx = __fadd_rn(bx, __fmul_rn(co.x, co.x));                              \
    by = __fadd_rn(by, __fmul_rn(co.y, co.y));                              \
    bz = __fadd_rn(bz, __fmul_rn(co.z, co.z));                              \
    bw = __fadd_rn(bw, __fmul_rn(co.w, co.w));
#define NP_TREE()                                                           \
    __fadd_rn(__fadd_rn(__fadd_rn(ax, ay), __fadd_rn(az, aw)),              \
              __fadd_rn(__fadd_rn(bx, by), __fadd_rn(bz, bw)))

__device__ __forceinline__ float np_pair_sq16(
        float4 c0, float4 c1, float4 c2, float4 c3,
        float4 c4, float4 c5, float4 c6, float4 c7,
        float4 c8, float4 c9, float4 c10, float4 c11,
        float4 c12, float4 c13, float4 c14, float4 c15) {
    NP_INIT(c0, c1)
    NP_ACC(c2, c3)  NP_ACC(c4, c5)  NP_ACC(c6, c7)
    NP_ACC(c8, c9)  NP_ACC(c10, c11) NP_ACC(c12, c13) NP_ACC(c14, c15)
    return NP_TREE();
}

// One step of the sequential dot chain: d += cr[i] . x_i  (order-exact).
#define DOT4(i)                                                             \
    q = cr[i];                                                              \
    d = __fmaf_rn(q.x, x##i.x, d);                                          \
    d = __fmaf_rn(q.y, x##i.y, d);                                          \
    d = __fmaf_rn(q.z, x##i.z, d);                                          \
    d = __fmaf_rn(q.w, x##i.w, d);

__global__ void __launch_bounds__(TPB)
__attribute__((amdgpu_waves_per_eu(3, 3)))
vq_kernel(
        const float* __restrict__ x, const float* __restrict__ cb,
        float* __restrict__ out_q, float* __restrict__ out_idx) {
    __shared__ float es[K_CB];     // 4 KB
    __shared__ int bks[TPB];       // 1 KB

    const int tid = threadIdx.x;
    const size_t row0 = (size_t)blockIdx.x * TPB;
    const size_t row  = row0 + tid;
    const float4* cb4 = reinterpret_cast<const float4*>(cb);

    // ---- phase A: block-local e_norms (numpy pairwise order) ----
#pragma unroll
    for (int j = 0; j < K_CB / TPB; ++j) {
        const int k = tid + TPB * j;
        const float4* cr = cb4 + (size_t)k * 16;
        float4 c0 = cr[0],  c1 = cr[1],  c2 = cr[2],  c3 = cr[3],
               c4 = cr[4],  c5 = cr[5],  c6 = cr[6],  c7 = cr[7],
               c8 = cr[8],  c9 = cr[9],  c10 = cr[10], c11 = cr[11],
               c12 = cr[12], c13 = cr[13], c14 = cr[14], c15 = cr[15];
        es[k] = np_pair_sq16(c0, c1, c2, c3, c4, c5, c6, c7,
                             c8, c9, c10, c11, c12, c13, c14, c15);
    }
    __syncthreads();

    // ---- phase B: my row in 16 NAMED float4 registers; x_norm ----
    const float4* xg = reinterpret_cast<const float4*>(x + row * D_DIM);
    float4 x0 = xg[0],  x1 = xg[1],  x2 = xg[2],  x3 = xg[3],
           x4 = xg[4],  x5 = xg[5],  x6 = xg[6],  x7 = xg[7],
           x8 = xg[8],  x9 = xg[9],  x10 = xg[10], x11 = xg[11],
           x12 = xg[12], x13 = xg[13], x14 = xg[14], x15 = xg[15];
    const float xn = np_pair_sq16(x0, x1, x2, x3, x4, x5, x6, x7,
                                  x8, x9, x10, x11, x12, x13, x14, x15);

    // ---- phase C: k-scan; cb addresses wave-uniform ----
    float best = FLT_MAX;
    int bestk = 0;
#pragma unroll 2
    for (int k = 0; k < K_CB; ++k) {
        const float4* cr = cb4 + (size_t)k * 16;
        float d = 0.f;
        float4 q;
        DOT4(0)  DOT4(1)  DOT4(2)  DOT4(3)
        DOT4(4)  DOT4(5)  DOT4(6)  DOT4(7)
        DOT4(8)  DOT4(9)  DOT4(10) DOT4(11)
        DOT4(12) DOT4(13) DOT4(14) DOT4(15)
        const float s = __fmaf_rn(-2.f, d, __fadd_rn(xn, es[k]));
        if (s < best) { best = s; bestk = k; }   // strict < = first-min
    }

    bks[tid] = bestk;
    __syncthreads();

    // ---- phase D: coalesced gather-write of x_quantized ----
    float4* oq = reinterpret_cast<float4*>(out_q + row0 * D_DIM);
#pragma unroll
    for (int j = 0; j < 16; ++j) {
        const int f = tid + TPB * j;     // 0..4095
        const int r = f >> 4, c = f & 15;
        oq[f] = cb4[(size_t)bks[r] * 16 + c];
    }
    out_idx[row] = (float)bestk;
}

extern "C" void kernel_launch(void* const* d_in, const int* in_sizes, int n_in,
                              void* d_out, int out_size, void* d_ws, size_t ws_size,
                              hipStream_t stream) {
    const float* x  = (const float*)d_in[0];
    const float* cb = (const float*)d_in[1];
    const int n_rows = in_sizes[0] / D_DIM;     // 262144

    float* out_q   = (float*)d_out;
    float* out_idx = out_q + (size_t)n_rows * D_DIM;

    vq_kernel<<<n_rows / TPB, TPB, 0, stream>>>(x, cb, out_q, out_idx);
}

// Round 11
// 480.463 us; speedup vs baseline: 1.8831x; 1.8831x over previous
//
#include <hip/hip_runtime.h>
#include <float.h>

// VectorQuantizer: N=262144 rows of D=64 fp32, K=1024 codebook rows.
// out = [x_quantized (N*D f32) | embed_inds (N, written as f32)]
//
// Bit-exact np-fp32 semantics (verified R4): score = fmaf(-2, seq-dot,
// fadd(xnorm, enorm)); pairwise-8 norms; strict < ascending k (first-min).
//
// R11: cb through LDS (broadcast ds_read_b128, ~30cyc, parallel to VALU)
// instead of wave-uniform VMEM (R4/R9/R10: ~200cyc, needs many waves to hide
// -> VALU density capped). 2 x-rows per thread in 32 NAMED float4s (R10
// proved named scalars stay register-resident; arrays don't). Two independent
// FMA chains/thread saturate issue within one wave; 2 waves/SIMD cover gaps.

static constexpr int D_DIM = 64;
static constexpr int K_CB  = 1024;
static constexpr int TPB   = 256;           // 4 waves
static constexpr int RPB   = 512;           // 2 rows/thread -> grid 512 (2 blocks/CU)
static constexpr int KTILE = 128;           // cb rows per LDS tile (32 KB)
static constexpr int NKT   = K_CB / KTILE;  // 8 tiles

// numpy pairwise-8 sum of squares of 64 values held as 16 float4s.
#define NP_INIT(c0, c1)                                                     \
    float ax = __fmul_rn(c0.x, c0.x), ay = __fmul_rn(c0.y, c0.y),           \
          az = __fmul_rn(c0.z, c0.z), aw = __fmul_rn(c0.w, c0.w);           \
    float bx = __fmul_rn(c1.x, c1.x), by = __fmul_rn(c1.y, c1.y),           \
          bz = __fmul_rn(c1.z, c1.z), bw = __fmul_rn(c1.w, c1.w);
#define NP_ACC(ce, co)                                                      \
    ax = __fadd_rn(ax, __fmul_rn(ce.x, ce.x));                              \
    ay = __fadd_rn(ay, __fmul_rn(ce.y, ce.y));                              \
    az = __fadd_rn(az, __fmul_rn(ce.z, ce.z));                              \
    aw = __fadd_rn(aw, __fmul_rn(ce.w, ce.w));                              \
    bx = __fadd_rn(bx, __fmul_rn(co.x, co.x));                              \
    by = __fadd_rn(by, __fmul_rn(co.y, co.y));                              \
    bz = __fadd_rn(bz, __fmul_rn(co.z, co.z));                              \
    bw = __fadd_rn(bw, __fmul_rn(co.w, co.w));
#define NP_TREE()                                                           \
    __fadd_rn(__fadd_rn(__fadd_rn(ax, ay), __fadd_rn(az, aw)),              \
              __fadd_rn(__fadd_rn(bx, by), __fadd_rn(bz, bw)))

__device__ __forceinline__ float np_pair_sq16(
        float4 c0, float4 c1, float4 c2, float4 c3,
        float4 c4, float4 c5, float4 c6, float4 c7,
        float4 c8, float4 c9, float4 c10, float4 c11,
        float4 c12, float4 c13, float4 c14, float4 c15) {
    NP_INIT(c0, c1)
    NP_ACC(c2, c3)  NP_ACC(c4, c5)  NP_ACC(c6, c7)
    NP_ACC(c8, c9)  NP_ACC(c10, c11) NP_ACC(c12, c13) NP_ACC(c14, c15)
    return NP_TREE();
}

// One step of BOTH rows' sequential dot chains (each chain order-exact in d).
#define DOT2(i)                                                             \
    q = cr[i];                                                              \
    dA = __fmaf_rn(q.x, a##i.x, dA); dB = __fmaf_rn(q.x, b##i.x, dB);       \
    dA = __fmaf_rn(q.y, a##i.y, dA); dB = __fmaf_rn(q.y, b##i.y, dB);       \
    dA = __fmaf_rn(q.z, a##i.z, dA); dB = __fmaf_rn(q.z, b##i.z, dB);       \
    dA = __fmaf_rn(q.w, a##i.w, dA); dB = __fmaf_rn(q.w, b##i.w, dB);

__global__ void __launch_bounds__(TPB)
__attribute__((amdgpu_waves_per_eu(2, 2)))
vq_kernel(
        const float* __restrict__ x, const float* __restrict__ cb,
        float* __restrict__ out_q, float* __restrict__ out_idx) {
    __shared__ float es[K_CB];           // 4 KB
    __shared__ float cbt[KTILE * D_DIM]; // 32 KB cb tile
    __shared__ int   bks[RPB];           // 2 KB

    const int tid = threadIdx.x;
    const size_t row0 = (size_t)blockIdx.x * RPB;
    const size_t rowA = row0 + tid;
    const size_t rowB = row0 + TPB + tid;
    const float4* cb4 = reinterpret_cast<const float4*>(cb);

    // ---- phase A: block-local e_norms (numpy pairwise order) ----
#pragma unroll
    for (int j = 0; j < K_CB / TPB; ++j) {
        const int k = tid + TPB * j;
        const float4* cr = cb4 + (size_t)k * 16;
        float4 c0 = cr[0],  c1 = cr[1],  c2 = cr[2],  c3 = cr[3],
               c4 = cr[4],  c5 = cr[5],  c6 = cr[6],  c7 = cr[7],
               c8 = cr[8],  c9 = cr[9],  c10 = cr[10], c11 = cr[11],
               c12 = cr[12], c13 = cr[13], c14 = cr[14], c15 = cr[15];
        es[k] = np_pair_sq16(c0, c1, c2, c3, c4, c5, c6, c7,
                             c8, c9, c10, c11, c12, c13, c14, c15);
    }

    // ---- phase B: my 2 rows in 32 NAMED float4 registers; x_norms ----
    const float4* ga = reinterpret_cast<const float4*>(x + rowA * D_DIM);
    float4 a0 = ga[0],  a1 = ga[1],  a2 = ga[2],  a3 = ga[3],
           a4 = ga[4],  a5 = ga[5],  a6 = ga[6],  a7 = ga[7],
           a8 = ga[8],  a9 = ga[9],  a10 = ga[10], a11 = ga[11],
           a12 = ga[12], a13 = ga[13], a14 = ga[14], a15 = ga[15];
    const float xnA = np_pair_sq16(a0, a1, a2, a3, a4, a5, a6, a7,
                                   a8, a9, a10, a11, a12, a13, a14, a15);
    const float4* gb = reinterpret_cast<const float4*>(x + rowB * D_DIM);
    float4 b0 = gb[0],  b1 = gb[1],  b2 = gb[2],  b3 = gb[3],
           b4 = gb[4],  b5 = gb[5],  b6 = gb[6],  b7 = gb[7],
           b8 = gb[8],  b9 = gb[9],  b10 = gb[10], b11 = gb[11],
           b12 = gb[12], b13 = gb[13], b14 = gb[14], b15 = gb[15];
    const float xnB = np_pair_sq16(b0, b1, b2, b3, b4, b5, b6, b7,
                                   b8, b9, b10, b11, b12, b13, b14, b15);

    // ---- phase C: k-scan over 8 LDS-staged cb tiles ----
    float bestA = FLT_MAX, bestB = FLT_MAX;
    int kA = 0, kB = 0;
    for (int t = 0; t < NKT; ++t) {
        __syncthreads();               // protect cbt from previous readers
        {                              // stage tile t: 2048 float4s, 8/thread
            const float4* src = cb4 + (size_t)t * KTILE * 16;
            float4* dst = reinterpret_cast<float4*>(cbt);
#pragma unroll
            for (int j = 0; j < 8; ++j) dst[tid + TPB * j] = src[tid + TPB * j];
        }
        __syncthreads();               // also makes es visible on t==0

#pragma unroll 2
        for (int kk = 0; kk < KTILE; ++kk) {
            const int k = t * KTILE + kk;
            const float4* cr = reinterpret_cast<const float4*>(&cbt[kk * D_DIM]);
            const float en = es[k];    // uniform broadcast read
            float dA = 0.f, dB = 0.f;
            float4 q;
            DOT2(0)  DOT2(1)  DOT2(2)  DOT2(3)
            DOT2(4)  DOT2(5)  DOT2(6)  DOT2(7)
            DOT2(8)  DOT2(9)  DOT2(10) DOT2(11)
            DOT2(12) DOT2(13) DOT2(14) DOT2(15)
            const float sA = __fmaf_rn(-2.f, dA, __fadd_rn(xnA, en));
            const float sB = __fmaf_rn(-2.f, dB, __fadd_rn(xnB, en));
            if (sA < bestA) { bestA = sA; kA = k; }   // strict < = first-min
            if (sB < bestB) { bestB = sB; kB = k; }
        }
    }

    bks[tid]       = kA;
    bks[TPB + tid] = kB;
    __syncthreads();

    // ---- phase D: coalesced gather-write of x_quantized (512 rows) ----
    float4* oq = reinterpret_cast<float4*>(out_q + row0 * D_DIM);
#pragma unroll
    for (int j = 0; j < RPB * 16 / TPB; ++j) {
        const int f = tid + TPB * j;     // 0..8191
        const int r = f >> 4, c = f & 15;
        oq[f] = cb4[(size_t)bks[r] * 16 + c];
    }
    out_idx[rowA] = (float)kA;
    out_idx[rowB] = (float)kB;
}

extern "C" void kernel_launch(void* const* d_in, const int* in_sizes, int n_in,
                              void* d_out, int out_size, void* d_ws, size_t ws_size,
                              hipStream_t stream) {
    const float* x  = (const float*)d_in[0];
    const float* cb = (const float*)d_in[1];
    const int n_rows = in_sizes[0] / D_DIM;     // 262144

    float* out_q   = (float*)d_out;
    float* out_idx = out_q + (size_t)n_rows * D_DIM;

    vq_kernel<<<n_rows / RPB, TPB, 0, stream>>>(x, cb, out_q, out_idx);
}